// Round 1
// baseline (580.516 us; speedup 1.0000x reference)
//
#include <hip/hip_runtime.h>

static constexpr int T_LEN  = 4096;              // time axis length
static constexpr int CHUNKS = T_LEN / (64 * 4);  // 16 float4 chunks per lane (lane owns 64 contiguous elems)
#define EPSV 1e-6f

typedef float vfloat4 __attribute__((ext_vector_type(4)));

// raw hw transcendentals: exp2/log2
__device__ __forceinline__ float fexp2(float x) { return __builtin_amdgcn_exp2f(x); }
__device__ __forceinline__ float flog2(float x) { return __builtin_amdgcn_logf(x); }

// order-preserving float<->uint transform (works for negatives too)
__device__ __forceinline__ unsigned int flip_f(float f) {
    unsigned int u = __float_as_uint(f);
    return u ^ ((u >> 31) ? 0xFFFFFFFFu : 0x80000000u);
}
__device__ __forceinline__ float unflip_f(unsigned int u) {
    u ^= ((u >> 31) ? 0x80000000u : 0xFFFFFFFFu);
    return __uint_as_float(u);
}

__global__ void init_ws(unsigned int* ws) {
    ws[0] = 0xFFFFFFFFu;  // min slot (transformed +max)
    ws[1] = 0x00000000u;  // max slot (transformed -max)
}

// Layout: 1 wave = 1 row. Lane L owns contiguous elements [L*64, L*64+64).
// Phase 1: preload row (16 dwordx4, full MLP), 4-way-ILP Horner for lane-local
//          decay-weighted sum. Phase 2: ONE 6-step shfl scan (ratio a^64).
// Phase 3: serial m-recurrence per lane (1 FMA chain) + independent pcen work.
// PASS 0 tracks min/max of u = E*(eps+M)^-alpha + delta (monotone pre-pow),
// converted to p-domain once per block. delta^r is dropped (shift-invariant).
template <int PASS>
__launch_bounds__(256, 4)
__global__ void pcen_pass(const float* __restrict__ E,
                          const float* __restrict__ sp,
                          const float* __restrict__ ap,
                          const float* __restrict__ dp,
                          const float* __restrict__ rp,
                          float* __restrict__ out,
                          unsigned int* __restrict__ ws,
                          int rows)
{
    const int tid  = threadIdx.x;
    const int lane = tid & 63;
    const int wv   = tid >> 6;
    const int row  = blockIdx.x * 4 + wv;

    float s = sp[0];
    s = fminf(fmaxf(s, 0.0f), 1.0f);
    const float a     = 1.0f - s;
    const float na    = -ap[0];
    const float delta = dp[0];
    const float r     = rp[0];

    // a^4 (Horner ratio) and a^64 (lane-scan ratio) by repeated squaring
    const float a2 = a * a, a4 = a2 * a2, a8 = a4 * a4,
                a16 = a8 * a8, a32 = a16 * a16, a64 = a32 * a32;

    // pwl = a^(64*lane): decay of the row seed up to this lane's segment
    float pwl;
    if (a > 0.0f) pwl = fexp2((float)(64 * lane) * flog2(a));
    else          pwl = (lane == 0) ? 1.0f : 0.0f;

    float scale = 0.0f, bias = 0.0f;
    if (PASS == 1) {
        const float pmin = unflip_f(ws[0]);
        const float pmax = unflip_f(ws[1]);
        const float inv  = 2.0f / (pmax - pmin);
        scale = inv;
        bias  = __builtin_fmaf(-pmin, inv, -1.0f);
    }

    float vmin = __builtin_inff(), vmax = -__builtin_inff();

    if (row < rows) {
        const float4* __restrict__ src =
            (const float4*)(E + (size_t)row * T_LEN) + lane * CHUNKS;

        // ---- Phase 1: preload whole row segment into registers (full MLP) ----
        float4 v[CHUNKS];
#pragma unroll
        for (int j = 0; j < CHUNKS; ++j) v[j] = src[j];

        // Lane-local weighted sum  W = s * sum_j a^(63-j) x_j
        // via 4 interleaved Horner chains (ratio a^4) for ILP.
        float w0 = 0.0f, w1 = 0.0f, w2 = 0.0f, w3 = 0.0f;
#pragma unroll
        for (int j = 0; j < CHUNKS; ++j) {
            w0 = __builtin_fmaf(a4, w0, v[j].x);
            w1 = __builtin_fmaf(a4, w1, v[j].y);
            w2 = __builtin_fmaf(a4, w2, v[j].z);
            w3 = __builtin_fmaf(a4, w3, v[j].w);
        }
        // W = s * (a^3 w0 + a^2 w1 + a w2 + w3)
        float W = s * __builtin_fmaf(a, __builtin_fmaf(a, __builtin_fmaf(a, w0, w1), w2), w3);

        // ---- Phase 2: single inclusive lane scan, ratio q = a^64 ----
        float S = W, t, q = a64;
        t = __shfl_up(S, 1, 64);  if (lane >= 1)  S = __builtin_fmaf(q, t, S); q *= q;
        t = __shfl_up(S, 2, 64);  if (lane >= 2)  S = __builtin_fmaf(q, t, S); q *= q;
        t = __shfl_up(S, 4, 64);  if (lane >= 4)  S = __builtin_fmaf(q, t, S); q *= q;
        t = __shfl_up(S, 8, 64);  if (lane >= 8)  S = __builtin_fmaf(q, t, S); q *= q;
        t = __shfl_up(S, 16, 64); if (lane >= 16) S = __builtin_fmaf(q, t, S); q *= q;
        t = __shfl_up(S, 32, 64); if (lane >= 32) S = __builtin_fmaf(q, t, S);

        float Sex = __shfl_up(S, 1, 64);   // exclusive: weighted-sum part of M[64*lane - 1]
        if (lane == 0) Sex = 0.0f;
        const float e0 = __shfl(v[0].x, 0, 64);  // row seed E[0] (M[-1] := E[0] trick)

        // M just before this lane's segment
        float m = __builtin_fmaf(pwl, e0, Sex);

        float* __restrict__ drow = out + (size_t)row * T_LEN + lane * (CHUNKS * 4);

        // ---- Phase 3: serial m-chain + independent pcen work per element ----
#pragma unroll
        for (int j = 0; j < CHUNKS; ++j) {
            float4 o;
            float x, u;

            x = v[j].x;
            m = __builtin_fmaf(a, m, s * x);
            u = __builtin_fmaf(x, fexp2(na * flog2(EPSV + m)), delta);
            if (PASS == 0) { vmin = fminf(vmin, u); vmax = fmaxf(vmax, u); }
            else            o.x = __builtin_fmaf(fexp2(r * flog2(u)), scale, bias);

            x = v[j].y;
            m = __builtin_fmaf(a, m, s * x);
            u = __builtin_fmaf(x, fexp2(na * flog2(EPSV + m)), delta);
            if (PASS == 0) { vmin = fminf(vmin, u); vmax = fmaxf(vmax, u); }
            else            o.y = __builtin_fmaf(fexp2(r * flog2(u)), scale, bias);

            x = v[j].z;
            m = __builtin_fmaf(a, m, s * x);
            u = __builtin_fmaf(x, fexp2(na * flog2(EPSV + m)), delta);
            if (PASS == 0) { vmin = fminf(vmin, u); vmax = fmaxf(vmax, u); }
            else            o.z = __builtin_fmaf(fexp2(r * flog2(u)), scale, bias);

            x = v[j].w;
            m = __builtin_fmaf(a, m, s * x);
            u = __builtin_fmaf(x, fexp2(na * flog2(EPSV + m)), delta);
            if (PASS == 0) { vmin = fminf(vmin, u); vmax = fmaxf(vmax, u); }
            else            o.w = __builtin_fmaf(fexp2(r * flog2(u)), scale, bias);

            if (PASS == 1) {
                // non-temporal store: keep E resident in L3 for reuse
                vfloat4 ov = { o.x, o.y, o.z, o.w };
                __builtin_nontemporal_store(ov, (vfloat4*)(drow + j * 4));
            }
        }
    }

    if (PASS == 0) {
        // wave reduce (u-domain)
        for (int off = 32; off >= 1; off >>= 1) {
            vmin = fminf(vmin, __shfl_xor(vmin, off, 64));
            vmax = fmaxf(vmax, __shfl_xor(vmax, off, 64));
        }
        __shared__ unsigned int smin, smax;
        if (tid == 0) { smin = 0xFFFFFFFFu; smax = 0u; }
        __syncthreads();
        if (lane == 0 && row < rows) {
            atomicMin(&smin, flip_f(vmin));
            atomicMax(&smax, flip_f(vmax));
        }
        __syncthreads();
        if (tid == 0) {
            // convert u-extrema -> p-domain (p = u^r monotone; minmax of both
            // endpoints handles either sign of r). Same instruction sequence as
            // PASS 1 per-element path -> bitwise-identical at the extremes.
            const float umin = unflip_f(smin);
            const float umax = unflip_f(smax);
            const float pl = fexp2(r * flog2(umin));
            const float ph = fexp2(r * flog2(umax));
            atomicMin(&ws[0], flip_f(fminf(pl, ph)));
            atomicMax(&ws[1], flip_f(fmaxf(pl, ph)));
        }
    }
}

extern "C" void kernel_launch(void* const* d_in, const int* in_sizes, int n_in,
                              void* d_out, int out_size, void* d_ws, size_t ws_size,
                              hipStream_t stream) {
    const float* E     = (const float*)d_in[0];
    const float* s     = (const float*)d_in[1];
    const float* alpha = (const float*)d_in[2];
    const float* delta = (const float*)d_in[3];
    const float* r     = (const float*)d_in[4];
    float* out         = (float*)d_out;
    unsigned int* ws   = (unsigned int*)d_ws;

    const int rows   = in_sizes[0] / T_LEN;   // 8192 for (32,256,4096)
    const int blocks = (rows + 3) / 4;        // 4 rows (waves) per 256-thread block

    hipLaunchKernelGGL(init_ws, dim3(1), dim3(1), 0, stream, ws);
    hipLaunchKernelGGL((pcen_pass<0>), dim3(blocks), dim3(256), 0, stream,
                       E, s, alpha, delta, r, out, ws, rows);
    hipLaunchKernelGGL((pcen_pass<1>), dim3(blocks), dim3(256), 0, stream,
                       E, s, alpha, delta, r, out, ws, rows);
}